// Round 11
// baseline (2077.521 us; speedup 1.0000x reference)
//
#include <hip/hip_runtime.h>

typedef unsigned int u32;
typedef unsigned long long u64;
typedef _Float16 f16;
typedef _Float16 f16x8 __attribute__((ext_vector_type(8)));
typedef float f32x4 __attribute__((ext_vector_type(4)));

#define DEV __device__ __forceinline__
#define SCP __HIP_MEMORY_SCOPE_AGENT
#define PINA(x) asm volatile("" : "+a"(x))

// ---------------- workspace layout (bytes), ~41.4 MB ----------------
constexpr size_t O_XG0   = 0;                          // [16][512][512] f32 : X@Wih0^T + b0 (p=4j+g cols)
constexpr size_t O_W0HI  = O_XG0   + 16ull*512*512*4;  // [512][128] f16 hi (Whh0, row p=4j+g)
constexpr size_t O_W0LO  = O_W0HI  + 512ull*128*2;
constexpr size_t O_WIHHI = O_W0LO  + 512ull*128*2;     // [512][128] f16 hi (Wih1 permuted)
constexpr size_t O_WIHLO = O_WIHHI + 512ull*128*2;
constexpr size_t O_WHHHI = O_WIHLO + 512ull*128*2;     // [512][128] f16 hi (Whh1 permuted)
constexpr size_t O_WHHLO = O_WHHHI + 512ull*128*2;
constexpr size_t O_B1P   = O_WHHLO + 512ull*128*2;     // [512] f32 bias1 permuted
constexpr size_t O_MSIG  = O_B1P   + 512*4;            // [1024][1024] f32 mask*sigmoid(adj_w)
constexpr size_t O_ESC   = O_MSIG  + 1024ull*1024*4;   // [16][1024]
constexpr size_t O_EDST  = O_ESC   + 16384*4;
constexpr size_t O_SBUF  = O_EDST  + 16384*4;          // [16][1024] attn-weighted gf
constexpr size_t O_PREPR = O_SBUF  + 16384*4;          // [16][128] price_repr
constexpr size_t O_WFG   = O_PREPR + 2048*4;           // [1024][64] folded Wf graph part
constexpr size_t O_H0HI  = O_WFG   + 65536ull*4;       // [513][16][64] u32 packed f16 col-pairs (hi)
constexpr size_t O_H0LO  = O_H0HI  + 513ull*16*64*4;
constexpr size_t O_P1    = O_H0LO  + 513ull*16*64*4;   // [513][16][512] f32 Wih1@h0+bias1 (p cols)
constexpr size_t O_FLG0  = O_P1    + 513ull*16*512*4;  // [513][2] u32: h0(s) of batch-group g ready
constexpr size_t O_FLGP  = O_FLG0  + 513ull*2*4;       // [513][2] u32: P1(s) of group g ready

struct U128 { u64 x, y; };
DEV f16x8 asf16x8(u64 a, u64 b){ U128 t; t.x=a; t.y=b; return __builtin_bit_cast(f16x8, t); }
DEV f32x4 asf32x4(u64 a, u64 b){ U128 t; t.x=a; t.y=b; return __builtin_bit_cast(f32x4, t); }
DEV u32 f16bits(f16 v){ return (u32)__builtin_bit_cast(unsigned short, v); }

DEV float sigm(float x){ x = fminf(fmaxf(x,-30.f),30.f); return __builtin_amdgcn_rcpf(1.f + __expf(-x)); }
DEV float tanh_(float x){ x = fminf(fmaxf(x,-15.f),15.f); float t = __expf(2.f*x); return (t-1.f)*__builtin_amdgcn_rcpf(t+1.f); }

DEV u32 FV(int s){ return 0x5AB00000u + (u32)s; }

DEV void spin1(const u32* p, u32 tv){
  int gd = 1<<18;   // bounded: guard-exhaust -> visible absmax failure, never a hang
  while (__hip_atomic_load(p,__ATOMIC_RELAXED,SCP)!=tv && --gd){}
  (void)__hip_atomic_load(p,__ATOMIC_ACQUIRE,SCP);
}

DEV void bar_lds(){
  asm volatile("s_waitcnt lgkmcnt(0)" ::: "memory");
  __builtin_amdgcn_s_barrier();
  __builtin_amdgcn_sched_barrier(0);
}

// =========================== setup kernel (identical to r7-r10) ===========================
__global__ __launch_bounds__(256) void k_setup(
    const float* __restrict__ price, const float* __restrict__ gf,
    const float* __restrict__ amask, const float* __restrict__ Wih0,
    const float* __restrict__ Whh0, const float* __restrict__ bih0, const float* __restrict__ bhh0,
    const float* __restrict__ Wih1, const float* __restrict__ Whh1,
    const float* __restrict__ bih1, const float* __restrict__ bhh1,
    const float* __restrict__ Wg, const float* __restrict__ a_src, const float* __restrict__ a_dst,
    const float* __restrict__ adj_w, const float* __restrict__ Wf,
    char* __restrict__ ws)
{
  const int tid = threadIdx.x;
  const int jb = blockIdx.x;
  __shared__ float P[16][64];
  __shared__ float Wt[64][128];

  if (jb < 2048) {
    const int tt = jb >> 2, p0 = (jb & 3) * 128;
    float* XG = (float*)(ws + O_XG0);
    { int idx = tid*4; int b = idx>>6, k = idx&63;
      f32x4 v = *(const f32x4*)(price + ((size_t)b*512 + tt)*64 + k);
      *(f32x4*)&P[b][k] = v; }
    { int c = tid>>1, kh = (tid&1)*32;
      int p = p0 + c; int row = (p&3)*128 + (p>>2);
      const float* src = Wih0 + row*64 + kh;
      #pragma unroll
      for (int kk=0; kk<32; kk+=4){ f32x4 v = *(const f32x4*)(src+kk);
        Wt[kh+kk+0][c]=v[0]; Wt[kh+kk+1][c]=v[1]; Wt[kh+kk+2][c]=v[2]; Wt[kh+kk+3][c]=v[3]; } }
    __syncthreads();
    { int c = tid & 127, hh2 = tid >> 7;
      int p = p0 + c; int row = (p&3)*128 + (p>>2);
      float bias = bih0[row] + bhh0[row];
      float acc[8];
      #pragma unroll
      for (int r2=0;r2<8;r2++) acc[r2] = bias;
      for (int k=0;k<64;k++){ float w = Wt[k][c];
        #pragma unroll
        for (int r2=0;r2<8;r2++) acc[r2] += w * P[hh2*8+r2][k]; }
      #pragma unroll
      for (int r2=0;r2<8;r2++)
        XG[((size_t)(hh2*8+r2)*512 + tt)*512 + p0 + c] = acc[r2]; }
  } else if (jb < 3072) {
    int idx = ((jb-2048)<<10) + tid*4;
    float* MS = (float*)(ws + O_MSIG);
    f32x4 m = *(const f32x4*)(amask+idx); f32x4 a = *(const f32x4*)(adj_w+idx);
    f32x4 o;
    #pragma unroll
    for (int e=0;e<4;e++) o[e] = m[e] * (1.f/(1.f+expf(-a[e])));
    *(f32x4*)(MS+idx) = o;
  } else if (jb < 3136) {
    unsigned short* HI = (unsigned short*)(ws+O_W0HI);
    unsigned short* LO = (unsigned short*)(ws+O_W0LO);
    int base = ((jb-3072)*256 + tid)*4;
    #pragma unroll
    for (int e=0;e<4;e++){ int idx = base+e; int p = idx>>7, k = idx&127;
      int row = (p&3)*128 + (p>>2);
      float w = Whh0[row*128 + k];
      f16 hi = (f16)w; f16 lo = (f16)((w - (float)hi)*4096.f);
      HI[idx] = (unsigned short)f16bits(hi); LO[idx] = (unsigned short)f16bits(lo); }
  } else if (jb < 3200) {
    unsigned short* HI = (unsigned short*)(ws+O_WIHHI);
    unsigned short* LO = (unsigned short*)(ws+O_WIHLO);
    int base = ((jb-3136)*256 + tid)*4;
    #pragma unroll
    for (int e=0;e<4;e++){ int idx = base+e; int p = idx>>7, k = idx&127;
      int row = (p&3)*128 + (p>>2);
      float w = Wih1[row*128 + k];
      f16 hi = (f16)w; f16 lo = (f16)((w - (float)hi)*4096.f);
      HI[idx] = (unsigned short)f16bits(hi); LO[idx] = (unsigned short)f16bits(lo); }
  } else if (jb < 3264) {
    unsigned short* HI = (unsigned short*)(ws+O_WHHHI);
    unsigned short* LO = (unsigned short*)(ws+O_WHHLO);
    int base = ((jb-3200)*256 + tid)*4;
    #pragma unroll
    for (int e=0;e<4;e++){ int idx = base+e; int p = idx>>7, k = idx&127;
      int row = (p&3)*128 + (p>>2);
      float w = Whh1[row*128 + k];
      f16 hi = (f16)w; f16 lo = (f16)((w - (float)hi)*4096.f);
      HI[idx] = (unsigned short)f16bits(hi); LO[idx] = (unsigned short)f16bits(lo); }
  } else if (jb < 3265) {
    float* B1 = (float*)(ws+O_B1P);
    for (int p = tid; p < 512; p += 256){ int row = (p&3)*128 + (p>>2); B1[p] = bih1[row]+bhh1[row]; }
  } else if (jb < 3281) {
    float cs = 0.f, cd = 0.f;
    for (int g=0; g<64; g++){ cs += Wg[g]*a_src[g]; cd += Wg[g]*a_dst[g]; }
    float* ESC = (float*)(ws+O_ESC); float* EDS = (float*)(ws+O_EDST);
    int base = (jb-3265)*1024 + tid*4;
    f32x4 g4 = *(const f32x4*)(gf+base);
    f32x4 e1, e2;
    #pragma unroll
    for (int e=0;e<4;e++){ e1[e] = g4[e]*cs; e2[e] = g4[e]*cd; }
    *(f32x4*)(ESC+base) = e1; *(f32x4*)(EDS+base) = e2;
  } else {
    float* WFG = (float*)(ws+O_WFG);
    int n = (jb-3281)*4 + (tid>>6); int f = tid & 63;
    float acc = 0.f;
    for (int g=0; g<64; g++) acc += Wg[g] * Wf[((size_t)(128 + n*64 + g))*64 + f];
    WFG[n*64 + f] = acc;
  }
}

// =========================== LDS for recurrence (r10 lane-read-order layout) ===========================
struct SM3 { u32 hbuf[2][1024]; };

// =========================== pipelined recurrence CU ===========================
// bg in {0,1}: batches bg*8..bg*8+7. Wave w owns h-cols [16w,16w+16); tile t = gate t.
// LAYER 0: consumes XG, publishes h0(s) + releases FLG0[s][bg] (deferred 1 step, vmcnt-counted).
// LAYER 1: spins FLGP, consumes P1 with 2-ahead prefetch; PREPR at s=512.
template<int LAYER>
DEV void rnn_pipe(char* __restrict__ ws, int bg, int tid, SM3* sm)
{
  const int lane = tid & 63, w = tid >> 6;
  const int r = lane & 15, q = lane >> 4;
  const int j = w*16 + r;
  const int b0 = bg*8 + 2*q;

  const u64* WHI = (const u64*)(ws + (LAYER ? O_WHHHI : O_W0HI));
  const u64* WLO = (const u64*)(ws + (LAYER ? O_WHHLO : O_W0LO));
  f16x8 Bhi[4][4], Blo[4][4];
  #pragma unroll
  for (int t=0;t<4;t++)
    #pragma unroll
    for (int ks=0;ks<4;ks++){
      int o = (4*j + t)*32 + ks*8 + q*2;
      Bhi[t][ks] = asf16x8(WHI[o], WHI[o+1]);
      Blo[t][ks] = asf16x8(WLO[o], WLO[o+1]);
    }
  #pragma unroll
  for (int t=0;t<4;t++)
    #pragma unroll
    for (int ks=0;ks<4;ks++){ PINA(Bhi[t][ks]); PINA(Blo[t][ks]); }

  u32* H0HIp = (u32*)(ws+O_H0HI);
  u32* H0LOp = (u32*)(ws+O_H0LO);
  const u64* P1u = (const u64*)(ws+O_P1);
  const float* XG  = (const float*)(ws+O_XG0);
  u32* FLG0p = (u32*)(ws+O_FLG0);
  const u32* FLGPp = (const u32*)(ws+O_FLGP);

  for (int idx = tid; idx < 2*1024; idx += 512) ((u32*)sm->hbuf)[idx] = 0u;

  // ---- 2-ahead pipeline of the additive term ----
  f32x4 xc[2], xN[2], xNN[2];
  u64 pc[2][2], pn[2][2], pnn[2][2];
  #pragma unroll
  for (int d=0; d<2; ++d){
    xc[d]=f32x4{0,0,0,0}; xN[d]=f32x4{0,0,0,0}; xNN[d]=f32x4{0,0,0,0};
    pc[d][0]=pc[d][1]=pn[d][0]=pn[d][1]=pnn[d][0]=pnn[d][1]=0;
  }
  if constexpr (!LAYER) {
    #pragma unroll
    for (int d=0; d<2; ++d){
      xc[d] = *(const f32x4*)(XG + ((size_t)((b0+d)*512 + 0))*512 + 4*j);
      xN[d] = *(const f32x4*)(XG + ((size_t)((b0+d)*512 + 1))*512 + 4*j);
    }
  } else {
    spin1(FLGPp + 1*2 + bg, FV(1));
    #pragma unroll
    for (int d=0; d<2; ++d){
      size_t o = ((size_t)(1*16 + b0+d)*512 + 4*j) >> 1;
      pc[d][0] = __hip_atomic_load(P1u+o,   __ATOMIC_RELAXED, SCP);
      pc[d][1] = __hip_atomic_load(P1u+o+1, __ATOMIC_RELAXED, SCP);
    }
    spin1(FLGPp + 2*2 + bg, FV(2));
    #pragma unroll
    for (int d=0; d<2; ++d){
      size_t o = ((size_t)(2*16 + b0+d)*512 + 4*j) >> 1;
      pn[d][0] = __hip_atomic_load(P1u+o,   __ATOMIC_RELAXED, SCP);
      pn[d][1] = __hip_atomic_load(P1u+o+1, __ATOMIC_RELAXED, SCP);
    }
  }
  float cst[2] = {0.f, 0.f};
  int cur = 0;
  __syncthreads();

  for (int s=1; s<=512; ++s){
    // ---- prefetch additive term for s+2 ----
    if constexpr (!LAYER) {
      int sp = (s<=510) ? (s+2) : 512;
      #pragma unroll
      for (int d=0; d<2; ++d)
        xNN[d] = *(const f32x4*)(XG + ((size_t)((b0+d)*512 + sp-1))*512 + 4*j);
      __builtin_amdgcn_sched_barrier(0);
    }

    // ---- MFMA: 32/wave; accA = A x Whi, accB = A x Wlo; A-read lane-ordered ----
    f32x4 accA[4], accB[4];
    #pragma unroll
    for (int t=0;t<4;t++){ accA[t]=f32x4{0,0,0,0}; accB[t]=f32x4{0,0,0,0}; }
    #pragma unroll
    for (int ks=0;ks<4;ks++){
      f16x8 av = *(const f16x8*)&sm->hbuf[cur][ks*256 + lane*4];
      #pragma unroll
      for (int t=0;t<4;t++){
        accA[t] = __builtin_amdgcn_mfma_f32_16x16x32_f16(av, Bhi[t][ks], accA[t], 0,0,0);
        accB[t] = __builtin_amdgcn_mfma_f32_16x16x32_f16(av, Blo[t][ks], accB[t], 0,0,0);
      }
    }

    // ---- layer1: spin + prefetch P1(s+2); spin is pre-satisfied (lag ~4 steps) ----
    if constexpr (LAYER) {
      int sp = (s+2 <= 512) ? (s+2) : 512;
      if (s+2 <= 512) spin1(FLGPp + sp*2 + bg, FV(sp));
      #pragma unroll
      for (int d=0; d<2; ++d){
        size_t o = ((size_t)(sp*16 + b0+d)*512 + 4*j) >> 1;
        pnn[d][0] = __hip_atomic_load(P1u+o,   __ATOMIC_RELAXED, SCP);
        pnn[d][1] = __hip_atomic_load(P1u+o+1, __ATOMIC_RELAXED, SCP);
      }
    }

    // ---- lane-local combine + epilogue ----
    float hv[2];
    #pragma unroll
    for (int d=0; d<2; ++d){
      float g0 = accA[0][2*d] + (accA[0][2*d+1] + accB[0][2*d])*(1.f/4096.f);
      float g1 = accA[1][2*d] + (accA[1][2*d+1] + accB[1][2*d])*(1.f/4096.f);
      float g2 = accA[2][2*d] + (accA[2][2*d+1] + accB[2][2*d])*(1.f/4096.f);
      float g3 = accA[3][2*d] + (accA[3][2*d+1] + accB[3][2*d])*(1.f/4096.f);
      f32x4 add = LAYER ? asf32x4(pc[d][0],pc[d][1]) : xc[d];
      float I = sigm(g0 + add[0]);
      float F = sigm(g1 + add[1]);
      float G = tanh_(g2 + add[2]);
      float O = sigm(g3 + add[3]);
      cst[d] = F*cst[d] + I*G;
      hv[d] = O * tanh_(cst[d]);
    }

    // ---- pack f16 hi/lo col-pairs, write LDS; L0: publish h0(s) ----
    u32 hp[2], lp[2];
    #pragma unroll
    for (int d=0; d<2; ++d){
      f16 hh = (f16)hv[d]; f16 hl = (f16)((hv[d] - (float)hh)*4096.f);
      u32 hb = f16bits(hh), lb = f16bits(hl);
      u32 oh = (u32)__shfl_xor((int)hb, 1, 64);
      u32 ol = (u32)__shfl_xor((int)lb, 1, 64);
      hp[d] = hb | (oh<<16); lp[d] = lb | (ol<<16);
    }
    int nxt = cur^1;
    if ((r & 1) == 0){
      const int cp = w*8 + (r>>1);
      const int wbase = (cp>>4)*256 + ((cp>>2)&3)*64 + 16*q + (cp&3);
      u32* hb8 = sm->hbuf[nxt];
      hb8[wbase+ 0] = hp[0];
      hb8[wbase+ 4] = lp[0];
      hb8[wbase+ 8] = hp[1];
      hb8[wbase+12] = lp[1];
      if constexpr (!LAYER){
        __hip_atomic_store(H0HIp + (s*16 + b0  )*64 + cp, hp[0], __ATOMIC_RELAXED, SCP);
        __hip_atomic_store(H0LOp + (s*16 + b0  )*64 + cp, lp[0], __ATOMIC_RELAXED, SCP);
        __hip_atomic_store(H0HIp + (s*16 + b0+1)*64 + cp, hp[1], __ATOMIC_RELAXED, SCP);
        __hip_atomic_store(H0LOp + (s*16 + b0+1)*64 + cp, lp[1], __ATOMIC_RELAXED, SCP);
      }
    }
    if constexpr (LAYER){
      if (s == 512){
        ((float*)(ws+O_PREPR))[(b0  )*128 + j] = hv[0];
        ((float*)(ws+O_PREPR))[(b0+1)*128 + j] = hv[1];
      }
    }

    // ---- barrier + deferred flag release (L0) ----
    if constexpr (!LAYER){
      // per step per wave: 2 XG loads + 4 publish stores = 6 vmem instrs.
      // vmcnt(4) leaves the 4 newest (this step's stores) in flight and GUARANTEES
      // everything older — including step s-1's publishes of every wave — is drained
      // before the barrier; flag(s-1) released after the barrier costs nothing.
      __builtin_amdgcn_sched_barrier(0);
      asm volatile("s_waitcnt vmcnt(4) lgkmcnt(0)" ::: "memory");
      __builtin_amdgcn_s_barrier();
      __builtin_amdgcn_sched_barrier(0);
      if (s>=2 && tid==0)
        __hip_atomic_store(FLG0p + (s-1)*2 + bg, FV(s-1), __ATOMIC_RELAXED, SCP);
    } else {
      bar_lds();
    }

    cur = nxt;
    #pragma unroll
    for (int d=0; d<2; ++d){
      xc[d]=xN[d]; xN[d]=xNN[d];
      pc[d][0]=pn[d][0]; pc[d][1]=pn[d][1];
      pn[d][0]=pnn[d][0]; pn[d][1]=pnn[d][1];
    }
  }

  if constexpr (!LAYER){
    asm volatile("s_waitcnt vmcnt(0)" ::: "memory");
    __syncthreads();
    if (tid==0) __hip_atomic_store(FLG0p + 512*2 + bg, FV(512), __ATOMIC_RELAXED, SCP);
  }
}

// =========================== pipelined GEMM CU: P1(s) for 8 batches of group g ===========================
DEV void gemm_pipe(char* __restrict__ ws, int g, int tid)
{
  const int lane = tid & 63, w = tid >> 6;
  const int r = lane & 15, q = lane >> 4;
  const int jj = w*16 + r;
  const int m = lane & 15;            // A row: batch (m>>1), hi if even, lo if odd
  const int bb = g*8 + (m>>1);

  const u64* WHI = (const u64*)(ws+O_WIHHI);
  const u64* WLO = (const u64*)(ws+O_WIHLO);
  f16x8 Bhi[4][4], Blo[4][4];
  #pragma unroll
  for (int t=0;t<4;t++)
    #pragma unroll
    for (int ks=0;ks<4;ks++){
      int o = (4*jj + t)*32 + ks*8 + q*2;
      Bhi[t][ks] = asf16x8(WHI[o], WHI[o+1]);
      Blo[t][ks] = asf16x8(WLO[o], WLO[o+1]);
    }
  #pragma unroll
  for (int t=0;t<4;t++)
    #pragma unroll
    for (int ks=0;ks<4;ks++){ PINA(Bhi[t][ks]); PINA(Blo[t][ks]); }

  float bias_t[4];
  #pragma unroll
  for (int t=0;t<4;t++) bias_t[t] = ((const float*)(ws+O_B1P))[4*jj + t];

  const u64* Hsel = (const u64*)(ws + ((m&1) ? O_H0LO : O_H0HI));
  float* P1f = (float*)(ws+O_P1);
  const u32* FLG0p = (const u32*)(ws+O_FLG0);
  u32* FLGPp = (u32*)(ws+O_FLGP);

  for (int s=1; s<=512; ++s){
    spin1(FLG0p + s*2 + g, FV(s));

    u64 A[4][2];
    #pragma unroll
    for (int ks=0;ks<4;ks++){
      size_t o = ((size_t)(s*16 + bb))*32 + ks*8 + q*2;
      A[ks][0] = __hip_atomic_load(Hsel+o,   __ATOMIC_RELAXED, SCP);
      A[ks][1] = __hip_atomic_load(Hsel+o+1, __ATOMIC_RELAXED, SCP);
    }
    f32x4 accA[4], accB[4];
    #pragma unroll
    for (int t=0;t<4;t++){ accA[t]=f32x4{0,0,0,0}; accB[t]=f32x4{0,0,0,0}; }
    #pragma unroll
    for (int ks=0;ks<4;ks++){
      f16x8 av = asf16x8(A[ks][0], A[ks][1]);
      #pragma unroll
      for (int t=0;t<4;t++){
        accA[t] = __builtin_amdgcn_mfma_f32_16x16x32_f16(av, Bhi[t][ks], accA[t], 0,0,0);
        accB[t] = __builtin_amdgcn_mfma_f32_16x16x32_f16(av, Blo[t][ks], accB[t], 0,0,0);
      }
    }
    #pragma unroll
    for (int t=0;t<4;t++){
      #pragma unroll
      for (int d=0; d<2; ++d){
        float v = accA[t][2*d] + (accA[t][2*d+1] + accB[t][2*d])*(1.f/4096.f) + bias_t[t];
        __hip_atomic_store(P1f + ((size_t)(s*16 + g*8 + 2*q + d))*512 + 4*jj + t,
                           v, __ATOMIC_RELAXED, SCP);
      }
    }
    __syncthreads();    // drains each wave's vmem (stores) before the release
    if (tid==0) __hip_atomic_store(FLGPp + s*2 + g, FV(s), __ATOMIC_RELAXED, SCP);
  }
}

// =========================== fused pipeline kernel: 6 blocks ===========================
__global__
__attribute__((amdgpu_flat_work_group_size(512,512), amdgpu_waves_per_eu(2,2)))
void k_main(char* __restrict__ ws)
{
  __shared__ SM3 sm;
  const int tid = threadIdx.x;
  const int bid = blockIdx.x;
  if (bid < 2)      rnn_pipe<0>(ws, bid,   tid, &sm);
  else if (bid < 4) gemm_pipe  (ws, bid-2, tid);
  else              rnn_pipe<1>(ws, bid-4, tid, &sm);
}

// =========================== attention ===========================
DEV float wredMax(float v){
  #pragma unroll
  for (int o=32;o;o>>=1) v = fmaxf(v, __shfl_xor(v,o,64));
  return v;
}
DEV float wredSum(float v){
  #pragma unroll
  for (int o=32;o;o>>=1) v += __shfl_xor(v,o,64);
  return v;
}

__global__ __launch_bounds__(512) void k_attn(const float* __restrict__ gf,
                                              char* __restrict__ ws, float* __restrict__ out)
{
  __shared__ float red[8];
  const int tid = threadIdx.x;
  const int row = blockIdx.x;
  const int b = row >> 10, i = row & 1023;
  const int w = tid >> 6;
  const float* MSIG = (const float*)(ws+O_MSIG);
  const float* ESC  = (const float*)(ws+O_ESC);
  const float* EDST = (const float*)(ws+O_EDST);
  float* SBUF = (float*)(ws+O_SBUF);

  const float ei = ESC[(b<<10)+i];
  float pv[2];
  float mx = -3.4e38f;
  #pragma unroll
  for (int k2=0;k2<2;k2++){
    int jj = tid + (k2<<9);
    float sc = (ei + EDST[(b<<10)+jj]) * MSIG[((size_t)i<<10)+jj];
    pv[k2] = sc; mx = fmaxf(mx, sc);
  }
  mx = wredMax(mx);
  if ((tid&63)==0) red[w] = mx;
  __syncthreads();
  mx = fmaxf(fmaxf(fmaxf(red[0],red[1]),fmaxf(red[2],red[3])),
             fmaxf(fmaxf(red[4],red[5]),fmaxf(red[6],red[7])));
  __syncthreads();

  float sum = 0.f;
  #pragma unroll
  for (int k2=0;k2<2;k2++){ pv[k2] = __expf(pv[k2]-mx); sum += pv[k2]; }
  sum = wredSum(sum);
  if ((tid&63)==0) red[w] = sum;
  __syncthreads();
  sum = red[0]+red[1]+red[2]+red[3]+red[4]+red[5]+red[6]+red[7];
  __syncthreads();

  const float rinv = 1.0f / sum;
  float sacc = 0.f;
  const size_t obase = 16 + ((size_t)row << 10);
  #pragma unroll
  for (int k2=0;k2<2;k2++){
    int jj = tid + (k2<<9);
    float a = pv[k2]*rinv;
    out[obase + jj] = a;
    sacc += a * gf[(b<<10)+jj];
  }
  sacc = wredSum(sacc);
  if ((tid&63)==0) red[w] = sacc;
  __syncthreads();
  if (tid==0) SBUF[row] = red[0]+red[1]+red[2]+red[3]+red[4]+red[5]+red[6]+red[7];
}

// =========================== final MLP ===========================
__global__ __launch_bounds__(256) void k_mlp(const float* __restrict__ Wf, const float* __restrict__ bf,
  const float* __restrict__ W1, const float* __restrict__ b1,
  const float* __restrict__ W2, const float* __restrict__ b2,
  const char* __restrict__ ws, float* __restrict__ out)
{
  __shared__ float sS[1024];
  __shared__ float sP[128];
  __shared__ float sR[256];
  __shared__ float sF[96];
  const int b = blockIdx.x, tid = threadIdx.x;
  const float* SBUF = (const float*)(ws+O_SBUF);
  const float* PREPR= (const float*)(ws+O_PREPR);
  const float* WFG  = (const float*)(ws+O_WFG);

  { f32x4 v = *(const f32x4*)(SBUF + (b<<10) + tid*4); *(f32x4*)&sS[tid*4] = v; }
  if (tid < 128) sP[tid] = PREPR[b*128 + tid];
  __syncthreads();

  const int f = tid & 63, kq = tid >> 6;
  float acc = 0.f;
  for (int n = kq*256; n < kq*256+256; ++n) acc += sS[n] * WFG[n*64 + f];
  if (kq == 0) {
    for (int k=0;k<128;k++) acc += sP[k] * Wf[k*64 + f];
    acc += bf[f];
  }
  sR[tid] = acc; __syncthreads();
  if (tid < 64) {
    float v = sR[tid] + sR[tid+64] + sR[tid+128] + sR[tid+192];
    sF[tid] = fmaxf(v, 0.f);
  }
  __syncthreads();
  if (tid < 32) {
    float a = 0.f;
    for (int k=0;k<64;k++) a += sF[k] * W1[k*32 + tid];
    sF[64+tid] = fmaxf(a + b1[tid], 0.f);
  }
  __syncthreads();
  if (tid == 0) {
    float a = 0.f;
    for (int k=0;k<32;k++) a += sF[64+k] * W2[k];
    out[b] = a + b2[0];
  }
}

// =========================== launch ===========================
extern "C" void kernel_launch(void* const* d_in, const int* in_sizes, int n_in,
                              void* d_out, int out_size, void* d_ws, size_t ws_size,
                              hipStream_t stream)
{
  const float* price = (const float*)d_in[0];
  const float* gf    = (const float*)d_in[1];
  const float* amask = (const float*)d_in[2];
  const float* Wih0  = (const float*)d_in[3];
  const float* Whh0  = (const float*)d_in[4];
  const float* bih0  = (const float*)d_in[5];
  const float* bhh0  = (const float*)d_in[6];
  const float* Wih1  = (const float*)d_in[7];
  const float* Whh1  = (const float*)d_in[8];
  const float* bih1  = (const float*)d_in[9];
  const float* bhh1  = (const float*)d_in[10];
  const float* Wg    = (const float*)d_in[11];
  const float* asrc  = (const float*)d_in[12];
  const float* adst  = (const float*)d_in[13];
  const float* adjw  = (const float*)d_in[14];
  const float* Wf    = (const float*)d_in[15];
  const float* bf    = (const float*)d_in[16];
  const float* W1    = (const float*)d_in[17];
  const float* b1    = (const float*)d_in[18];
  const float* W2    = (const float*)d_in[19];
  const float* b2    = (const float*)d_in[20];
  char* ws = (char*)d_ws;
  float* out = (float*)d_out;

  k_setup<<<dim3(3537), dim3(256), 0, stream>>>(price, gf, amask, Wih0, Whh0, bih0, bhh0,
                                                Wih1, Whh1, bih1, bhh1, Wg, asrc, adst, adjw, Wf, ws);
  k_attn<<<dim3(16384), dim3(512), 0, stream>>>(gf, ws, out);
  k_main<<<dim3(6), dim3(512), 0, stream>>>(ws);
  k_mlp<<<dim3(16), dim3(256), 0, stream>>>(Wf, bf, W1, b1, W2, b2, (const char*)ws, out);
}